// Round 14
// baseline (25514.445 us; speedup 1.0000x reference)
//
#include <hip/hip_runtime.h>

// Problem constants
#define T_SEQ   8192
#define N_RES   2048
#define K_IN    512

// Geometry: 64 blocks x 512 threads (8 waves); 32 rows/block, 4 rows/wave.
#define G_BLOCKS 64
#define B_THREADS 512
#define ROWS_PER_WAVE 4
#define ROWS_PER_BLOCK 32
static_assert(G_BLOCKS * ROWS_PER_BLOCK == N_RES, "row partition mismatch");

#define INV_SQRT_N 0.022097086912079612f

// Phase encoding: packet float e = phi*(v + ENC_OFF), phi alternates per ring
// generation (phi(g) = ((g>>1)&1) ? -1 : +1, slot = g&1). |v| <= 0.0222 so
// |e| in [0.078, 0.122]. Ready iff phi_expected*e > ENC_THR; stale (gen-2)
// packet has opposite phi -> not-ready; zero-init -> not-ready. Every 32-bit
// word is independently self-validating -> non-atomic 16B accesses are legal.
#define ENC_OFF 0.1f
#define ENC_THR 0.05f

typedef unsigned long long u64;
typedef unsigned int u32;
typedef float f32x2 __attribute__((ext_vector_type(2)));
typedef float f32x4 __attribute__((ext_vector_type(4)));

__device__ __forceinline__ float fast_tanh(float v) {
    float e = __expf(2.0f * v);
    return 1.0f - 2.0f / (e + 1.0f);
}

// Coherent 16B ops at the agent coherence point (sc0 sc1 = bypass L1+L2).
__device__ __forceinline__ void store_f4_coh(float* p, f32x4 v) {
    asm volatile("global_store_dwordx4 %0, %1, off sc0 sc1"
                 :: "v"(p), "v"(v) : "memory");
}
__device__ __forceinline__ f32x4 load_f4_coh(const float* p) {
    f32x4 r;
    asm volatile("global_load_dwordx4 %0, %1, off sc0 sc1\n\t"
                 "s_waitcnt vmcnt(0)"
                 : "=v"(r) : "v"(p) : "memory");
    return r;
}

// Plain (L1/L2-cached) prefetch issue — volatile pins program order so the
// issue point stays BEFORE the poll; latency hides under the rendezvous wait.
#define ISSUE4NC(dst, ptr, OFFSTR) \
    asm volatile("global_load_dwordx4 %0, %1, off offset:" OFFSTR \
                 : "=v"(dst) : "v"(ptr))

// DPP full-wave sum; ctrl is a compile-time constant (template param).
template<int CTRL>
__device__ __forceinline__ float dpp_add(float a) {
    int s = __builtin_amdgcn_update_dpp(0, __float_as_int(a), CTRL, 0xf, 0xf, false);
    return a + __int_as_float(s);
}
__device__ __forceinline__ float wave_sum(float a) {
    a = dpp_add<0x111>(a);  // row_shr:1
    a = dpp_add<0x112>(a);  // row_shr:2
    a = dpp_add<0x114>(a);  // row_shr:4
    a = dpp_add<0x118>(a);  // row_shr:8
    a = dpp_add<0x142>(a);  // row_bcast:15
    a = dpp_add<0x143>(a);  // row_bcast:31
    return __int_as_float(__builtin_amdgcn_readlane(__float_as_int(a), 63));
}

#define KEEP2(v) asm("" : "+v"(v))

// d_ws layout: ring [2][2048] f32 (16 KB)
__global__ __launch_bounds__(B_THREADS, 2)
void reservoir_v14(const float* __restrict__ input,   // [T_SEQ][K_IN]
                   const float* __restrict__ state0,  // [N_RES]
                   const float* __restrict__ W_in,    // [N_RES][K_IN]
                   const float* __restrict__ W_res,   // [N_RES][N_RES]
                   float* __restrict__ out,           // [T_SEQ+1][N_RES]
                   float* __restrict__ ring)
{
    const int tid  = threadIdx.x;
    const int lane = tid & 63;
    const int wave = tid >> 6;
    const int blk  = blockIdx.x;
    const int r0   = blk * ROWS_PER_BLOCK + wave * ROWS_PER_WAVE;

    __shared__ float s_lds[2][N_RES];   // double-buffered state (16 KB)

    // ---- input-weight fragments (small; pinned, may stay resident) ----
    f32x2 wi2[ROWS_PER_WAVE][4];
    #pragma unroll
    for (int k = 0; k < ROWS_PER_WAVE; ++k) {
        const float* irow = W_in + (size_t)(r0 + k) * K_IN;
        #pragma unroll
        for (int i = 0; i < 2; ++i) {
            float4 w = *reinterpret_cast<const float4*>(irow + 4 * lane + 256 * i);
            wi2[k][2 * i]     = (f32x2){w.x, w.y};
            wi2[k][2 * i + 1] = (f32x2){w.z, w.w};
        }
    }

    // W_res row bases for this lane's columns {4l+256i}: rows 0,1 prefetched
    // via asm (A: i=0..3, B: i=4..7 — 13-bit signed offset caps at +4095B);
    // rows 2,3 compiler-streamed.
    const float* w0A = W_res + (size_t)(r0 + 0) * N_RES + 4 * lane;
    const float* w0B = w0A + 1024;
    const float* w1A = W_res + (size_t)(r0 + 1) * N_RES + 4 * lane;
    const float* w1B = w1A + 1024;
    const float* w2A = W_res + (size_t)(r0 + 2) * N_RES + 4 * lane;
    const float* w3A = W_res + (size_t)(r0 + 3) * N_RES + 4 * lane;

    // out row 0 = initial state
    if (blk == 0)
        for (int j = tid; j < N_RES; j += B_THREADS) out[j] = state0[j];

    // s_0 -> LDS buffer 0 (covered by the in-loop __syncthreads at t=0)
    #pragma unroll
    for (int i = 0; i < 4; ++i)
        s_lds[0][i * 512 + tid] = state0[i * 512 + tid];

    // x row 0 as packed pairs (layout matches wi cols {4l+256i})
    f32x2 xv[4];
    {
        float4 a = *reinterpret_cast<const float4*>(input + 4 * lane);
        float4 b = *reinterpret_cast<const float4*>(input + 4 * lane + 256);
        xv[0] = (f32x2){a.x, a.y}; xv[1] = (f32x2){a.z, a.w};
        xv[2] = (f32x2){b.x, b.y}; xv[3] = (f32x2){b.z, b.w};
    }

    for (int t = 0; t < T_SEQ; ++t) {
        const int buf = t & 1;

        // issue x_{t+1} prefetch first (HBM latency >= L2's)
        f32x2 xn[4] = {xv[0], xv[1], xv[2], xv[3]};
        if (t + 1 < T_SEQ) {
            const float* xr = input + (size_t)(t + 1) * K_IN;
            float4 a = *reinterpret_cast<const float4*>(xr + 4 * lane);
            float4 b = *reinterpret_cast<const float4*>(xr + 4 * lane + 256);
            xn[0] = (f32x2){a.x, a.y}; xn[1] = (f32x2){a.z, a.w};
            xn[2] = (f32x2){b.x, b.y}; xn[3] = (f32x2){b.z, b.w};
        }

        // ---- pre-poll weight prefetch, rows 0,1 (16x dwordx4 = 128B/lane):
        // L2 latency overlaps the rendezvous wait below.
        f32x4 p0[8], p1[8];
        ISSUE4NC(p0[0], w0A, "0");    ISSUE4NC(p0[1], w0A, "1024");
        ISSUE4NC(p0[2], w0A, "2048"); ISSUE4NC(p0[3], w0A, "3072");
        ISSUE4NC(p0[4], w0B, "0");    ISSUE4NC(p0[5], w0B, "1024");
        ISSUE4NC(p0[6], w0B, "2048"); ISSUE4NC(p0[7], w0B, "3072");
        ISSUE4NC(p1[0], w1A, "0");    ISSUE4NC(p1[1], w1A, "1024");
        ISSUE4NC(p1[2], w1A, "2048"); ISSUE4NC(p1[3], w1A, "3072");
        ISSUE4NC(p1[4], w1B, "0");    ISSUE4NC(p1[5], w1B, "1024");
        ISSUE4NC(p1[6], w1B, "2048"); ISSUE4NC(p1[7], w1B, "3072");

        if (t > 0) {
            // ---- single-load poll: thread tid owns state cols [4tid, 4tid+4)
            const float phi = ((t >> 1) & 1) ? -1.0f : 1.0f;
            const float* rp = ring + (buf << 11) + 4 * tid;
            f32x4 e;
            for (;;) {
                e = load_f4_coh(rp);    // vmcnt(0) inside also drains prefetches
                if (phi * e.x > ENC_THR && phi * e.y > ENC_THR &&
                    phi * e.z > ENC_THR && phi * e.w > ENC_THR) break;
                __builtin_amdgcn_s_sleep(1);
            }
            float4 sv = make_float4(fmaf(phi, e.x, -ENC_OFF),
                                    fmaf(phi, e.y, -ENC_OFF),
                                    fmaf(phi, e.z, -ENC_OFF),
                                    fmaf(phi, e.w, -ENC_OFF));
            *reinterpret_cast<float4*>(&s_lds[buf][4 * tid]) = sv;
        }
        __syncthreads();

        // fence the prefetched registers before use (rule #18: waitcnt + tie
        // + sched_barrier so VALU uses can't be hoisted above the wait)
        asm volatile("s_waitcnt vmcnt(0)"
                     : "+v"(p0[0]), "+v"(p0[1]), "+v"(p0[2]), "+v"(p0[3]),
                       "+v"(p0[4]), "+v"(p0[5]), "+v"(p0[6]), "+v"(p0[7]),
                       "+v"(p1[0]), "+v"(p1[1]), "+v"(p1[2]), "+v"(p1[3]),
                       "+v"(p1[4]), "+v"(p1[5]), "+v"(p1[6]), "+v"(p1[7])
                     :: "memory");
        __builtin_amdgcn_sched_barrier(0);

        // ---- state fragment from LDS as packed pairs ----
        f32x2 sp[16];
        #pragma unroll
        for (int i = 0; i < 8; ++i) {
            float4 s = *reinterpret_cast<const float4*>(&s_lds[buf][4 * lane + 256 * i]);
            sp[2 * i]     = (f32x2){s.x, s.y};
            sp[2 * i + 1] = (f32x2){s.z, s.w};
        }

        // ---- dots: rows 0,1 from prefetched regs; rows 2,3 streamed ----
        f32x2 acc2[ROWS_PER_WAVE];
        #pragma unroll
        for (int k = 0; k < ROWS_PER_WAVE; ++k) {
            f32x2 a = (f32x2){0.0f, 0.0f};
            #pragma unroll
            for (int i = 0; i < 4; ++i)
                a = __builtin_elementwise_fma(wi2[k][i], xv[i], a);
            acc2[k] = a;
        }
        #pragma unroll
        for (int i = 0; i < 8; ++i) {
            acc2[0] = __builtin_elementwise_fma((f32x2){p0[i].x, p0[i].y},
                                                sp[2 * i], acc2[0]);
            acc2[0] = __builtin_elementwise_fma((f32x2){p0[i].z, p0[i].w},
                                                sp[2 * i + 1], acc2[0]);
            acc2[1] = __builtin_elementwise_fma((f32x2){p1[i].x, p1[i].y},
                                                sp[2 * i], acc2[1]);
            acc2[1] = __builtin_elementwise_fma((f32x2){p1[i].z, p1[i].w},
                                                sp[2 * i + 1], acc2[1]);
        }
        #pragma unroll
        for (int i = 0; i < 8; ++i) {
            float4 w2 = *reinterpret_cast<const float4*>(w2A + 256 * i);
            float4 w3 = *reinterpret_cast<const float4*>(w3A + 256 * i);
            acc2[2] = __builtin_elementwise_fma((f32x2){w2.x, w2.y}, sp[2 * i], acc2[2]);
            acc2[2] = __builtin_elementwise_fma((f32x2){w2.z, w2.w}, sp[2 * i + 1], acc2[2]);
            acc2[3] = __builtin_elementwise_fma((f32x2){w3.x, w3.y}, sp[2 * i], acc2[3]);
            acc2[3] = __builtin_elementwise_fma((f32x2){w3.z, w3.w}, sp[2 * i + 1], acc2[3]);
        }

        // ---- DPP full-wave reduce (4 rows interleaved), results uniform ----
        const float t0 = wave_sum(acc2[0].x + acc2[0].y);
        const float t1 = wave_sum(acc2[1].x + acc2[1].y);
        const float t2 = wave_sum(acc2[2].x + acc2[2].y);
        const float t3 = wave_sum(acc2[3].x + acc2[3].y);

        const float v0 = fast_tanh(t0) * INV_SQRT_N;
        const float v1 = fast_tanh(t1) * INV_SQRT_N;
        const float v2 = fast_tanh(t2) * INV_SQRT_N;
        const float v3 = fast_tanh(t3) * INV_SQRT_N;

        const int   slotn = (t + 1) & 1;
        const float phin  = (((t + 1) >> 1) & 1) ? -1.0f : 1.0f;
        if (lane == 0) {
            f32x4 pk = {phin * (v0 + ENC_OFF), phin * (v1 + ENC_OFF),
                        phin * (v2 + ENC_OFF), phin * (v3 + ENC_OFF)};
            store_f4_coh(ring + (slotn << 11) + r0, pk);
        } else if (lane == 2) {
            // per-wave out store (rows r0..r0+3) — off the critical path
            *reinterpret_cast<float4*>(out + (size_t)(t + 1) * N_RES + r0) =
                make_float4(v0, v1, v2, v3);
        }

        // ---- pin the small input-weight set across the back edge ----
        #pragma unroll
        for (int k = 0; k < ROWS_PER_WAVE; ++k) {
            #pragma unroll
            for (int i = 0; i < 4; ++i) KEEP2(wi2[k][i]);
        }

        #pragma unroll
        for (int i = 0; i < 4; ++i) xv[i] = xn[i];
    }
}

extern "C" void kernel_launch(void* const* d_in, const int* in_sizes, int n_in,
                              void* d_out, int out_size, void* d_ws, size_t ws_size,
                              hipStream_t stream) {
    const float* input  = (const float*)d_in[0];
    const float* state0 = (const float*)d_in[1];
    const float* W_in   = (const float*)d_in[2];
    const float* W_res  = (const float*)d_in[3];
    float* out  = (float*)d_out;
    float* ring = (float*)d_ws;

    // zero = "not ready" for both phases; re-cleared on every call/replay
    hipMemsetAsync(d_ws, 0, 2 * N_RES * sizeof(float), stream);

    void* args[] = { (void*)&input, (void*)&state0, (void*)&W_in, (void*)&W_res,
                     (void*)&out, (void*)&ring };
    hipLaunchCooperativeKernel((const void*)reservoir_v14,
                               dim3(G_BLOCKS), dim3(B_THREADS),
                               args, 0, stream);
}

// Round 15
// 21712.210 us; speedup vs baseline: 1.1751x; 1.1751x over previous
//
#include <hip/hip_runtime.h>

// Problem constants
#define T_SEQ   8192
#define N_RES   2048
#define K_IN    512

// Geometry: 64 blocks x 512 threads (8 waves); 32 rows/block, 4 rows/wave.
#define G_BLOCKS 64
#define B_THREADS 512
#define ROWS_PER_WAVE 4
#define ROWS_PER_BLOCK 32
static_assert(G_BLOCKS * ROWS_PER_BLOCK == N_RES, "row partition mismatch");

#define INV_SQRT_N 0.022097086912079612f

// Phase encoding (unchanged from v11): packet float e = phi*(v + ENC_OFF),
// phi(g) = ((g>>1)&1) ? -1 : +1, slot = g&1. |v| <= 0.0222 -> |e| in
// [0.078, 0.122]. Ready iff phi_expected*e > ENC_THR; stale/zero -> not-ready.
#define ENC_OFF 0.1f
#define ENC_THR 0.05f

typedef unsigned int u32;
typedef float f32x2 __attribute__((ext_vector_type(2)));
typedef float f32x4 __attribute__((ext_vector_type(4)));
typedef _Float16 h16x2 __attribute__((ext_vector_type(2)));

__device__ __forceinline__ float fast_tanh(float v) {
    float e = __expf(2.0f * v);
    return 1.0f - 2.0f / (e + 1.0f);
}

// Coherent 16B ops at the agent coherence point (sc0 sc1 = bypass L1+L2).
__device__ __forceinline__ void store_f4_coh(float* p, f32x4 v) {
    asm volatile("global_store_dwordx4 %0, %1, off sc0 sc1"
                 :: "v"(p), "v"(v) : "memory");
}
__device__ __forceinline__ f32x4 load_f4_coh(const float* p) {
    f32x4 r;
    asm volatile("global_load_dwordx4 %0, %1, off sc0 sc1\n\t"
                 "s_waitcnt vmcnt(0)"
                 : "=v"(r) : "v"(p) : "memory");
    return r;
}

// f16x2 dot with f32 accumulate: v_dot2_f32_f16 (1 instr / 2 cols).
__device__ __forceinline__ float dot2(u32 w, u32 s, float acc) {
    h16x2 wv = __builtin_bit_cast(h16x2, w);
    h16x2 sv = __builtin_bit_cast(h16x2, s);
#if __has_builtin(__builtin_amdgcn_fdot2)
    return __builtin_amdgcn_fdot2(wv, sv, acc, false);
#else
    return fmaf((float)wv.x, (float)sv.x, fmaf((float)wv.y, (float)sv.y, acc));
#endif
}
__device__ __forceinline__ u32 pkrtz(float a, float b) {
    return __builtin_bit_cast(u32, __builtin_amdgcn_cvt_pkrtz(a, b));
}

// DPP full-wave sum (verified correct in r13); result uniform via readlane.
template<int CTRL>
__device__ __forceinline__ float dpp_add(float a) {
    int s = __builtin_amdgcn_update_dpp(0, __float_as_int(a), CTRL, 0xf, 0xf, false);
    return a + __int_as_float(s);
}
__device__ __forceinline__ float wave_sum(float a) {
    a = dpp_add<0x111>(a);  // row_shr:1
    a = dpp_add<0x112>(a);  // row_shr:2
    a = dpp_add<0x114>(a);  // row_shr:4
    a = dpp_add<0x118>(a);  // row_shr:8
    a = dpp_add<0x142>(a);  // row_bcast:15
    a = dpp_add<0x143>(a);  // row_bcast:31
    return __int_as_float(__builtin_amdgcn_readlane(__float_as_int(a), 63));
}

#define KEEP2(v) asm("" : "+v"(v))

// d_ws layout: ring [2][2048] f32 (16 KB)
__global__ __launch_bounds__(B_THREADS, 2)
void reservoir_v15(const float* __restrict__ input,   // [T_SEQ][K_IN]
                   const float* __restrict__ state0,  // [N_RES]
                   const float* __restrict__ W_in,    // [N_RES][K_IN]
                   const float* __restrict__ W_res,   // [N_RES][N_RES]
                   float* __restrict__ out,           // [T_SEQ+1][N_RES]
                   float* __restrict__ ring)
{
    const int tid  = threadIdx.x;
    const int lane = tid & 63;
    const int wave = tid >> 6;
    const int blk  = blockIdx.x;
    const int r0   = blk * ROWS_PER_BLOCK;            // block's first row

    // 128 KB f16 weights + 8 KB f16 state double-buffer = 136 KB LDS
    __shared__ u32 wlds[ROWS_PER_BLOCK][N_RES / 2];
    __shared__ u32 s16[2][N_RES / 2];

    // ---- prologue: W_res rows -> f16x2 pairs in LDS (one-time) ----
    for (int m = tid; m < ROWS_PER_BLOCK * (N_RES / 2); m += B_THREADS) {
        const int row = m >> 10, p = m & 1023;
        const float2 w = *reinterpret_cast<const float2*>(
            W_res + (size_t)(r0 + row) * N_RES + 2 * p);
        wlds[row][p] = pkrtz(w.x, w.y);
    }

    // ---- W_in fragments (f32, cols {4l+256i}) — small, kept in regs ----
    f32x2 wi2[ROWS_PER_WAVE][4];
    #pragma unroll
    for (int k = 0; k < ROWS_PER_WAVE; ++k) {
        const float* irow = W_in + (size_t)(r0 + wave * ROWS_PER_WAVE + k) * K_IN;
        #pragma unroll
        for (int i = 0; i < 2; ++i) {
            float4 w = *reinterpret_cast<const float4*>(irow + 4 * lane + 256 * i);
            wi2[k][2 * i]     = (f32x2){w.x, w.y};
            wi2[k][2 * i + 1] = (f32x2){w.z, w.w};
        }
    }

    // out row 0 = initial state
    if (blk == 0)
        for (int j = tid; j < N_RES; j += B_THREADS) out[j] = state0[j];

    // s_0 -> f16 LDS buffer 0 (covered by in-loop __syncthreads at t=0)
    {
        float4 s = *reinterpret_cast<const float4*>(state0 + 4 * tid);
        s16[0][2 * tid]     = pkrtz(s.x, s.y);
        s16[0][2 * tid + 1] = pkrtz(s.z, s.w);
    }

    // x row 0 as packed pairs (layout matches wi cols {4l+256i})
    f32x2 xv[4];
    {
        float4 a = *reinterpret_cast<const float4*>(input + 4 * lane);
        float4 b = *reinterpret_cast<const float4*>(input + 4 * lane + 256);
        xv[0] = (f32x2){a.x, a.y}; xv[1] = (f32x2){a.z, a.w};
        xv[2] = (f32x2){b.x, b.y}; xv[3] = (f32x2){b.z, b.w};
    }

    for (int t = 0; t < T_SEQ; ++t) {
        const int buf = t & 1;

        // issue x_{t+1} prefetch; HBM latency hides under the poll
        f32x2 xn[4] = {xv[0], xv[1], xv[2], xv[3]};
        if (t + 1 < T_SEQ) {
            const float* xr = input + (size_t)(t + 1) * K_IN;
            float4 a = *reinterpret_cast<const float4*>(xr + 4 * lane);
            float4 b = *reinterpret_cast<const float4*>(xr + 4 * lane + 256);
            xn[0] = (f32x2){a.x, a.y}; xn[1] = (f32x2){a.z, a.w};
            xn[2] = (f32x2){b.x, b.y}; xn[3] = (f32x2){b.z, b.w};
        }

        // ---- W_in contribution PRE-poll (depends only on x_t) ----
        f32x2 accin[ROWS_PER_WAVE];
        #pragma unroll
        for (int k = 0; k < ROWS_PER_WAVE; ++k) {
            f32x2 a = (f32x2){0.0f, 0.0f};
            #pragma unroll
            for (int i = 0; i < 4; ++i)
                a = __builtin_elementwise_fma(wi2[k][i], xv[i], a);
            accin[k] = a;
        }

        if (t > 0) {
            // ---- single-load poll: thread tid owns state cols [4tid, 4tid+4)
            const float phi = ((t >> 1) & 1) ? -1.0f : 1.0f;
            const float* rp = ring + (buf << 11) + 4 * tid;
            f32x4 e;
            for (;;) {
                e = load_f4_coh(rp);
                if (phi * e.x > ENC_THR && phi * e.y > ENC_THR &&
                    phi * e.z > ENC_THR && phi * e.w > ENC_THR) break;
                __builtin_amdgcn_s_sleep(1);
            }
            // decode -> f16x2 pairs -> LDS (8B, coalesced)
            s16[buf][2 * tid]     = pkrtz(fmaf(phi, e.x, -ENC_OFF),
                                          fmaf(phi, e.y, -ENC_OFF));
            s16[buf][2 * tid + 1] = pkrtz(fmaf(phi, e.z, -ENC_OFF),
                                          fmaf(phi, e.w, -ENC_OFF));
        }
        __syncthreads();

        // ---- state pairs for this lane's cols [32l, 32l+32): 4x b128 ----
        uint4 su[4];
        #pragma unroll
        for (int j = 0; j < 4; ++j)
            su[j] = *reinterpret_cast<const uint4*>(&s16[buf][16 * lane + 4 * j]);

        // ---- per-row: 4x b128 weight reads + 16 fdot2 ----
        float acc[ROWS_PER_WAVE];
        #pragma unroll
        for (int k = 0; k < ROWS_PER_WAVE; ++k) {
            const int row = wave * ROWS_PER_WAVE + k;
            float a = accin[k].x + accin[k].y;
            #pragma unroll
            for (int j = 0; j < 4; ++j) {
                uint4 wu = *reinterpret_cast<const uint4*>(
                    &wlds[row][16 * lane + 4 * j]);
                a = dot2(wu.x, su[j].x, a);
                a = dot2(wu.y, su[j].y, a);
                a = dot2(wu.z, su[j].z, a);
                a = dot2(wu.w, su[j].w, a);
            }
            acc[k] = a;
        }

        // ---- DPP full-wave reduce (4 rows), uniform results ----
        const float t0 = wave_sum(acc[0]);
        const float t1 = wave_sum(acc[1]);
        const float t2 = wave_sum(acc[2]);
        const float t3 = wave_sum(acc[3]);

        const float v0 = fast_tanh(t0) * INV_SQRT_N;
        const float v1 = fast_tanh(t1) * INV_SQRT_N;
        const float v2 = fast_tanh(t2) * INV_SQRT_N;
        const float v3 = fast_tanh(t3) * INV_SQRT_N;

        const int   wr0   = r0 + wave * ROWS_PER_WAVE;
        const int   slotn = (t + 1) & 1;
        const float phin  = (((t + 1) >> 1) & 1) ? -1.0f : 1.0f;
        if (lane == 0) {
            f32x4 pk = {phin * (v0 + ENC_OFF), phin * (v1 + ENC_OFF),
                        phin * (v2 + ENC_OFF), phin * (v3 + ENC_OFF)};
            store_f4_coh(ring + (slotn << 11) + wr0, pk);
        } else if (lane == 2) {
            // per-wave out store (rows wr0..wr0+3) — off the critical path
            *reinterpret_cast<float4*>(out + (size_t)(t + 1) * N_RES + wr0) =
                make_float4(v0, v1, v2, v3);
        }

        // ---- pin the small input-weight set across the back edge ----
        #pragma unroll
        for (int k = 0; k < ROWS_PER_WAVE; ++k) {
            #pragma unroll
            for (int i = 0; i < 4; ++i) KEEP2(wi2[k][i]);
        }

        #pragma unroll
        for (int i = 0; i < 4; ++i) xv[i] = xn[i];
    }
}

extern "C" void kernel_launch(void* const* d_in, const int* in_sizes, int n_in,
                              void* d_out, int out_size, void* d_ws, size_t ws_size,
                              hipStream_t stream) {
    const float* input  = (const float*)d_in[0];
    const float* state0 = (const float*)d_in[1];
    const float* W_in   = (const float*)d_in[2];
    const float* W_res  = (const float*)d_in[3];
    float* out  = (float*)d_out;
    float* ring = (float*)d_ws;

    // zero = "not ready" for both phases; re-cleared on every call/replay
    hipMemsetAsync(d_ws, 0, 2 * N_RES * sizeof(float), stream);

    void* args[] = { (void*)&input, (void*)&state0, (void*)&W_in, (void*)&W_res,
                     (void*)&out, (void*)&ring };
    hipLaunchCooperativeKernel((const void*)reservoir_v15,
                               dim3(G_BLOCKS), dim3(B_THREADS),
                               args, 0, stream);
}

// Round 16
// 15835.519 us; speedup vs baseline: 1.6112x; 1.3711x over previous
//
#include <hip/hip_runtime.h>

// Problem constants
#define T_SEQ   8192
#define N_RES   2048
#define K_IN    512

// Geometry: 64 blocks x 512 threads (8 waves); 32 rows/block, 4 rows/wave.
#define G_BLOCKS 64
#define B_THREADS 512
#define ROWS_PER_WAVE 4
#define ROWS_PER_BLOCK 32
static_assert(G_BLOCKS * ROWS_PER_BLOCK == N_RES, "row partition mismatch");

#define INV_SQRT_N 0.022097086912079612f

// Phase encoding (v11): packet float e = phi*(v + ENC_OFF),
// phi(g) = ((g>>1)&1) ? -1 : +1, slot = g&1. |v| <= 0.0222 -> |e| in
// [0.078, 0.122]. Ready iff phi_expected*e > ENC_THR; stale/zero -> not-ready.
#define ENC_OFF 0.1f
#define ENC_THR 0.05f

typedef unsigned int u32;
typedef float f32x2 __attribute__((ext_vector_type(2)));
typedef float f32x4 __attribute__((ext_vector_type(4)));
typedef _Float16 h16x2 __attribute__((ext_vector_type(2)));

__device__ __forceinline__ float fast_tanh(float v) {
    float e = __expf(2.0f * v);
    return 1.0f - 2.0f / (e + 1.0f);
}

// Coherent 16B ops at the agent coherence point (sc0 sc1 = bypass L1+L2).
__device__ __forceinline__ void store_f4_coh(float* p, f32x4 v) {
    asm volatile("global_store_dwordx4 %0, %1, off sc0 sc1"
                 :: "v"(p), "v"(v) : "memory");
}
__device__ __forceinline__ f32x4 load_f4_coh(const float* p) {
    f32x4 r;
    asm volatile("global_load_dwordx4 %0, %1, off sc0 sc1\n\t"
                 "s_waitcnt vmcnt(0)"
                 : "=v"(r) : "v"(p) : "memory");
    return r;
}

// f16x2 dot with f32 accumulate: v_dot2_f32_f16 (1 instr / 2 cols).
__device__ __forceinline__ float dot2(u32 w, u32 s, float acc) {
    h16x2 wv = __builtin_bit_cast(h16x2, w);
    h16x2 sv = __builtin_bit_cast(h16x2, s);
#if __has_builtin(__builtin_amdgcn_fdot2)
    return __builtin_amdgcn_fdot2(wv, sv, acc, false);
#else
    return fmaf((float)wv.x, (float)sv.x, fmaf((float)wv.y, (float)sv.y, acc));
#endif
}
__device__ __forceinline__ u32 pkrtz(float a, float b) {
    return __builtin_bit_cast(u32, __builtin_amdgcn_cvt_pkrtz(a, b));
}

// DPP full-wave sum (verified r13); result uniform via readlane(63).
template<int CTRL>
__device__ __forceinline__ float dpp_add(float a) {
    int s = __builtin_amdgcn_update_dpp(0, __float_as_int(a), CTRL, 0xf, 0xf, false);
    return a + __int_as_float(s);
}
__device__ __forceinline__ float wave_sum(float a) {
    a = dpp_add<0x111>(a);  // row_shr:1
    a = dpp_add<0x112>(a);  // row_shr:2
    a = dpp_add<0x114>(a);  // row_shr:4
    a = dpp_add<0x118>(a);  // row_shr:8
    a = dpp_add<0x142>(a);  // row_bcast:15
    a = dpp_add<0x143>(a);  // row_bcast:31
    return __int_as_float(__builtin_amdgcn_readlane(__float_as_int(a), 63));
}

#define KEEP2(v) asm("" : "+v"(v))

// d_ws layout: ring [2][2048] f32 (16 KB)
__global__ __launch_bounds__(B_THREADS, 2)
void reservoir_v16(const float* __restrict__ input,   // [T_SEQ][K_IN]
                   const float* __restrict__ state0,  // [N_RES]
                   const float* __restrict__ W_in,    // [N_RES][K_IN]
                   const float* __restrict__ W_res,   // [N_RES][N_RES]
                   float* __restrict__ out,           // [T_SEQ+1][N_RES]
                   float* __restrict__ ring)
{
    const int tid  = threadIdx.x;
    const int lane = tid & 63;
    const int wave = tid >> 6;
    const int blk  = blockIdx.x;
    const int r0   = blk * ROWS_PER_BLOCK;            // block's first row

    // 128 KB f16 weights + 8 KB f16 state double-buffer = 136 KB LDS
    __shared__ u32 wlds[ROWS_PER_BLOCK][N_RES / 2];
    __shared__ u32 s16[2][N_RES / 2];

    // ---- prologue: W_res rows -> f16x2 pairs in LDS (one-time) ----
    for (int m = tid; m < ROWS_PER_BLOCK * (N_RES / 2); m += B_THREADS) {
        const int row = m >> 10, p = m & 1023;
        const float2 w = *reinterpret_cast<const float2*>(
            W_res + (size_t)(r0 + row) * N_RES + 2 * p);
        wlds[row][p] = pkrtz(w.x, w.y);
    }

    // ---- W_in fragments (f32, cols {4l+256i}) — small, kept in regs ----
    f32x2 wi2[ROWS_PER_WAVE][4];
    #pragma unroll
    for (int k = 0; k < ROWS_PER_WAVE; ++k) {
        const float* irow = W_in + (size_t)(r0 + wave * ROWS_PER_WAVE + k) * K_IN;
        #pragma unroll
        for (int i = 0; i < 2; ++i) {
            float4 w = *reinterpret_cast<const float4*>(irow + 4 * lane + 256 * i);
            wi2[k][2 * i]     = (f32x2){w.x, w.y};
            wi2[k][2 * i + 1] = (f32x2){w.z, w.w};
        }
    }

    // out row 0 = initial state
    if (blk == 0)
        for (int j = tid; j < N_RES; j += B_THREADS) out[j] = state0[j];

    // s_0 -> f16 LDS buffer 0 (covered by in-loop __syncthreads at t=0)
    {
        float4 s = *reinterpret_cast<const float4*>(state0 + 4 * tid);
        s16[0][2 * tid]     = pkrtz(s.x, s.y);
        s16[0][2 * tid + 1] = pkrtz(s.z, s.w);
    }

    // x row 0 as packed pairs (layout matches wi cols {4l+256i})
    f32x2 xv[4];
    {
        float4 a = *reinterpret_cast<const float4*>(input + 4 * lane);
        float4 b = *reinterpret_cast<const float4*>(input + 4 * lane + 256);
        xv[0] = (f32x2){a.x, a.y}; xv[1] = (f32x2){a.z, a.w};
        xv[2] = (f32x2){b.x, b.y}; xv[3] = (f32x2){b.z, b.w};
    }

    for (int t = 0; t < T_SEQ; ++t) {
        const int buf = t & 1;

        // issue x_{t+1} prefetch; HBM latency hides under the poll
        f32x2 xn[4] = {xv[0], xv[1], xv[2], xv[3]};
        if (t + 1 < T_SEQ) {
            const float* xr = input + (size_t)(t + 1) * K_IN;
            float4 a = *reinterpret_cast<const float4*>(xr + 4 * lane);
            float4 b = *reinterpret_cast<const float4*>(xr + 4 * lane + 256);
            xn[0] = (f32x2){a.x, a.y}; xn[1] = (f32x2){a.z, a.w};
            xn[2] = (f32x2){b.x, b.y}; xn[3] = (f32x2){b.z, b.w};
        }

        // ---- W_in contribution PRE-poll (depends only on x_t) ----
        f32x2 accin[ROWS_PER_WAVE];
        #pragma unroll
        for (int k = 0; k < ROWS_PER_WAVE; ++k) {
            f32x2 a = (f32x2){0.0f, 0.0f};
            #pragma unroll
            for (int i = 0; i < 4; ++i)
                a = __builtin_elementwise_fma(wi2[k][i], xv[i], a);
            accin[k] = a;
        }

        if (t > 0) {
            // ---- single-load poll: thread tid owns state cols [4tid, 4tid+4)
            const float phi = ((t >> 1) & 1) ? -1.0f : 1.0f;
            const float* rp = ring + (buf << 11) + 4 * tid;
            f32x4 e;
            for (;;) {
                e = load_f4_coh(rp);
                if (phi * e.x > ENC_THR && phi * e.y > ENC_THR &&
                    phi * e.z > ENC_THR && phi * e.w > ENC_THR) break;
                __builtin_amdgcn_s_sleep(1);
            }
            // decode -> f16x2 pairs -> LDS (8B, coalesced)
            s16[buf][2 * tid]     = pkrtz(fmaf(phi, e.x, -ENC_OFF),
                                          fmaf(phi, e.y, -ENC_OFF));
            s16[buf][2 * tid + 1] = pkrtz(fmaf(phi, e.z, -ENC_OFF),
                                          fmaf(phi, e.w, -ENC_OFF));
        }
        __syncthreads();

        // ---- CONFLICT-FIX: lane l owns f16 cols {8l+512j}: read word index
        // 4*lane + 256*j -> each b128 covers 1KB contiguous per wave (full
        // rate, m134 pattern; banks 4l..4l+3 mod 32). Was 16*lane+4*j = 64B
        // stride = 32-way conflict (r15's 1e9 SQ_LDS_BANK_CONFLICT).
        uint4 su[4];
        #pragma unroll
        for (int j = 0; j < 4; ++j)
            su[j] = *reinterpret_cast<const uint4*>(&s16[buf][4 * lane + 256 * j]);

        // ---- per-row: 4x b128 weight reads + 16 fdot2 ----
        float acc[ROWS_PER_WAVE];
        #pragma unroll
        for (int k = 0; k < ROWS_PER_WAVE; ++k) {
            const int row = wave * ROWS_PER_WAVE + k;
            float a = accin[k].x + accin[k].y;
            #pragma unroll
            for (int j = 0; j < 4; ++j) {
                uint4 wu = *reinterpret_cast<const uint4*>(
                    &wlds[row][4 * lane + 256 * j]);
                a = dot2(wu.x, su[j].x, a);
                a = dot2(wu.y, su[j].y, a);
                a = dot2(wu.z, su[j].z, a);
                a = dot2(wu.w, su[j].w, a);
            }
            acc[k] = a;
        }

        // ---- DPP full-wave reduce (4 rows), uniform results ----
        const float t0 = wave_sum(acc[0]);
        const float t1 = wave_sum(acc[1]);
        const float t2 = wave_sum(acc[2]);
        const float t3 = wave_sum(acc[3]);

        const float v0 = fast_tanh(t0) * INV_SQRT_N;
        const float v1 = fast_tanh(t1) * INV_SQRT_N;
        const float v2 = fast_tanh(t2) * INV_SQRT_N;
        const float v3 = fast_tanh(t3) * INV_SQRT_N;

        const int   wr0   = r0 + wave * ROWS_PER_WAVE;
        const int   slotn = (t + 1) & 1;
        const float phin  = (((t + 1) >> 1) & 1) ? -1.0f : 1.0f;
        if (lane == 0) {
            f32x4 pk = {phin * (v0 + ENC_OFF), phin * (v1 + ENC_OFF),
                        phin * (v2 + ENC_OFF), phin * (v3 + ENC_OFF)};
            store_f4_coh(ring + (slotn << 11) + wr0, pk);
        } else if (lane == 2) {
            // per-wave out store (rows wr0..wr0+3) — off the critical path
            *reinterpret_cast<float4*>(out + (size_t)(t + 1) * N_RES + wr0) =
                make_float4(v0, v1, v2, v3);
        }

        // ---- pin the small input-weight set across the back edge ----
        #pragma unroll
        for (int k = 0; k < ROWS_PER_WAVE; ++k) {
            #pragma unroll
            for (int i = 0; i < 4; ++i) KEEP2(wi2[k][i]);
        }

        #pragma unroll
        for (int i = 0; i < 4; ++i) xv[i] = xn[i];
    }
}

extern "C" void kernel_launch(void* const* d_in, const int* in_sizes, int n_in,
                              void* d_out, int out_size, void* d_ws, size_t ws_size,
                              hipStream_t stream) {
    const float* input  = (const float*)d_in[0];
    const float* state0 = (const float*)d_in[1];
    const float* W_in   = (const float*)d_in[2];
    const float* W_res  = (const float*)d_in[3];
    float* out  = (float*)d_out;
    float* ring = (float*)d_ws;

    // zero = "not ready" for both phases; re-cleared on every call/replay
    hipMemsetAsync(d_ws, 0, 2 * N_RES * sizeof(float), stream);

    void* args[] = { (void*)&input, (void*)&state0, (void*)&W_in, (void*)&W_res,
                     (void*)&out, (void*)&ring };
    hipLaunchCooperativeKernel((const void*)reservoir_v16,
                               dim3(G_BLOCKS), dim3(B_THREADS),
                               args, 0, stream);
}

// Round 17
// 15425.870 us; speedup vs baseline: 1.6540x; 1.0266x over previous
//
#include <hip/hip_runtime.h>

// Problem constants
#define T_SEQ   8192
#define N_RES   2048
#define K_IN    512

// Geometry: 64 blocks x 512 threads (8 waves); 32 rows/block, 4 rows/wave.
#define G_BLOCKS 64
#define B_THREADS 512
#define ROWS_PER_WAVE 4
#define ROWS_PER_BLOCK 32
static_assert(G_BLOCKS * ROWS_PER_BLOCK == N_RES, "row partition mismatch");

#define INV_SQRT_N 0.022097086912079612f

// f16 phase encoding: packet half e = phi*(v + 0.1), phi(g) = ((g>>1)&1)?-1:+1,
// slot = g&1. |v| <= 0.0222 -> |e| in [0.078, 0.122]. Ready iff phi*e > 0.05.
// Stale (gen-2) packet has opposite phi -> not-ready; zero-init -> not-ready.
// Sterbenz: e - 0.1 is EXACT in f16 for e in [0.05, 0.2], so decode adds no
// error beyond the producer's pkrtz rounding (<= 1 ulp at 0.1 ~ 6e-5).
#define ENC_OFF 0.1f
#define ENC_THR 0.05f

typedef unsigned int u32;
typedef float f32x2 __attribute__((ext_vector_type(2)));
typedef _Float16 h16x2 __attribute__((ext_vector_type(2)));

__device__ __forceinline__ float fast_tanh(float v) {
    float e = __expf(2.0f * v);
    return 1.0f - 2.0f / (e + 1.0f);
}

// Coherent 8B ops at the agent coherence point (sc0 sc1 = bypass L1+L2).
__device__ __forceinline__ void store_u2_coh(u32* p, uint2 v) {
    asm volatile("global_store_dwordx2 %0, %1, off sc0 sc1"
                 :: "v"(p), "v"(v) : "memory");
}
__device__ __forceinline__ uint2 load_u2_coh(const u32* p) {
    uint2 r;
    asm volatile("global_load_dwordx2 %0, %1, off sc0 sc1\n\t"
                 "s_waitcnt vmcnt(0)"
                 : "=v"(r) : "v"(p) : "memory");
    return r;
}

// f16x2 dot with f32 accumulate: v_dot2_f32_f16 (1 instr / 2 cols).
__device__ __forceinline__ float dot2(u32 w, u32 s, float acc) {
    h16x2 wv = __builtin_bit_cast(h16x2, w);
    h16x2 sv = __builtin_bit_cast(h16x2, s);
#if __has_builtin(__builtin_amdgcn_fdot2)
    return __builtin_amdgcn_fdot2(wv, sv, acc, false);
#else
    return fmaf((float)wv.x, (float)sv.x, fmaf((float)wv.y, (float)sv.y, acc));
#endif
}
__device__ __forceinline__ u32 pkrtz(float a, float b) {
    return __builtin_bit_cast(u32, __builtin_amdgcn_cvt_pkrtz(a, b));
}

// DPP full-wave sum (verified r13); result uniform via readlane(63).
template<int CTRL>
__device__ __forceinline__ float dpp_add(float a) {
    int s = __builtin_amdgcn_update_dpp(0, __float_as_int(a), CTRL, 0xf, 0xf, false);
    return a + __int_as_float(s);
}
__device__ __forceinline__ float wave_sum(float a) {
    a = dpp_add<0x111>(a);  // row_shr:1
    a = dpp_add<0x112>(a);  // row_shr:2
    a = dpp_add<0x114>(a);  // row_shr:4
    a = dpp_add<0x118>(a);  // row_shr:8
    a = dpp_add<0x142>(a);  // row_bcast:15
    a = dpp_add<0x143>(a);  // row_bcast:31
    return __int_as_float(__builtin_amdgcn_readlane(__float_as_int(a), 63));
}

#define KEEP2(v) asm("" : "+v"(v))

// d_ws layout: ring [2][1024] u32 (8 KB) — each u32 = 2 phase-encoded f16
__global__ __launch_bounds__(B_THREADS, 2)
void reservoir_v17(const float* __restrict__ input,   // [T_SEQ][K_IN]
                   const float* __restrict__ state0,  // [N_RES]
                   const float* __restrict__ W_in,    // [N_RES][K_IN]
                   const float* __restrict__ W_res,   // [N_RES][N_RES]
                   float* __restrict__ out,           // [T_SEQ+1][N_RES]
                   u32* __restrict__ ring)
{
    const int tid  = threadIdx.x;
    const int lane = tid & 63;
    const int wave = tid >> 6;
    const int blk  = blockIdx.x;
    const int r0   = blk * ROWS_PER_BLOCK;            // block's first row

    // 128 KB f16 weights + 8 KB f16 state double-buffer = 136 KB LDS
    __shared__ u32 wlds[ROWS_PER_BLOCK][N_RES / 2];
    __shared__ u32 s16[2][N_RES / 2];

    // ---- prologue: W_res rows -> f16x2 pairs in LDS (one-time) ----
    for (int m = tid; m < ROWS_PER_BLOCK * (N_RES / 2); m += B_THREADS) {
        const int row = m >> 10, p = m & 1023;
        const float2 w = *reinterpret_cast<const float2*>(
            W_res + (size_t)(r0 + row) * N_RES + 2 * p);
        wlds[row][p] = pkrtz(w.x, w.y);
    }

    // ---- W_in fragments (f32, cols {4l+256i}) — small, kept in regs ----
    f32x2 wi2[ROWS_PER_WAVE][4];
    #pragma unroll
    for (int k = 0; k < ROWS_PER_WAVE; ++k) {
        const float* irow = W_in + (size_t)(r0 + wave * ROWS_PER_WAVE + k) * K_IN;
        #pragma unroll
        for (int i = 0; i < 2; ++i) {
            float4 w = *reinterpret_cast<const float4*>(irow + 4 * lane + 256 * i);
            wi2[k][2 * i]     = (f32x2){w.x, w.y};
            wi2[k][2 * i + 1] = (f32x2){w.z, w.w};
        }
    }

    // out row 0 = initial state
    if (blk == 0)
        for (int j = tid; j < N_RES; j += B_THREADS) out[j] = state0[j];

    // s_0 -> f16 LDS buffer 0 (covered by in-loop __syncthreads at t=0)
    {
        float4 s = *reinterpret_cast<const float4*>(state0 + 4 * tid);
        s16[0][2 * tid]     = pkrtz(s.x, s.y);
        s16[0][2 * tid + 1] = pkrtz(s.z, s.w);
    }

    // x row 0 as packed pairs (layout matches wi cols {4l+256i})
    f32x2 xv[4];
    {
        float4 a = *reinterpret_cast<const float4*>(input + 4 * lane);
        float4 b = *reinterpret_cast<const float4*>(input + 4 * lane + 256);
        xv[0] = (f32x2){a.x, a.y}; xv[1] = (f32x2){a.z, a.w};
        xv[2] = (f32x2){b.x, b.y}; xv[3] = (f32x2){b.z, b.w};
    }

    for (int t = 0; t < T_SEQ; ++t) {
        const int buf = t & 1;

        // issue x_{t+1} prefetch; HBM latency hides under the poll
        f32x2 xn[4] = {xv[0], xv[1], xv[2], xv[3]};
        if (t + 1 < T_SEQ) {
            const float* xr = input + (size_t)(t + 1) * K_IN;
            float4 a = *reinterpret_cast<const float4*>(xr + 4 * lane);
            float4 b = *reinterpret_cast<const float4*>(xr + 4 * lane + 256);
            xn[0] = (f32x2){a.x, a.y}; xn[1] = (f32x2){a.z, a.w};
            xn[2] = (f32x2){b.x, b.y}; xn[3] = (f32x2){b.z, b.w};
        }

        // ---- W_in contribution PRE-poll (depends only on x_t) ----
        f32x2 accin[ROWS_PER_WAVE];
        #pragma unroll
        for (int k = 0; k < ROWS_PER_WAVE; ++k) {
            f32x2 a = (f32x2){0.0f, 0.0f};
            #pragma unroll
            for (int i = 0; i < 4; ++i)
                a = __builtin_elementwise_fma(wi2[k][i], xv[i], a);
            accin[k] = a;
        }

        if (t > 0) {
            // ---- single 8B poll: thread tid owns state cols [4tid, 4tid+4)
            const bool neg = ((t >> 1) & 1) != 0;
            const _Float16 phih  = neg ? (_Float16)-1.0f : (_Float16)1.0f;
            const _Float16 thrh  = (_Float16)ENC_THR;
            const h16x2 phi2  = {phih, phih};
            const h16x2 noff2 = {(_Float16)-ENC_OFF, (_Float16)-ENC_OFF};
            const u32* rp = ring + (buf << 10) + 2 * tid;
            h16x2 p0, p1;
            for (;;) {
                uint2 e = load_u2_coh(rp);
                p0 = __builtin_bit_cast(h16x2, e.x);
                p1 = __builtin_bit_cast(h16x2, e.y);
                _Float16 m0 = phih * p0.x < phih * p0.y ? phih * p0.x : phih * p0.y;
                _Float16 m1 = phih * p1.x < phih * p1.y ? phih * p1.x : phih * p1.y;
                if ((m0 < m1 ? m0 : m1) > thrh) break;
                __builtin_amdgcn_s_sleep(1);
            }
            // decode (exact Sterbenz subtract) -> f16 LDS, 8B coalesced
            s16[buf][2 * tid]     = __builtin_bit_cast(
                u32, __builtin_elementwise_fma(phi2, p0, noff2));
            s16[buf][2 * tid + 1] = __builtin_bit_cast(
                u32, __builtin_elementwise_fma(phi2, p1, noff2));
        }
        __syncthreads();

        // ---- conflict-free reads: lane l owns f16 cols {8l+512j} ----
        uint4 su[4];
        #pragma unroll
        for (int j = 0; j < 4; ++j)
            su[j] = *reinterpret_cast<const uint4*>(&s16[buf][4 * lane + 256 * j]);

        // ---- per-row: 4x b128 weight reads + 16 fdot2 ----
        float acc[ROWS_PER_WAVE];
        #pragma unroll
        for (int k = 0; k < ROWS_PER_WAVE; ++k) {
            const int row = wave * ROWS_PER_WAVE + k;
            float a = accin[k].x + accin[k].y;
            #pragma unroll
            for (int j = 0; j < 4; ++j) {
                uint4 wu = *reinterpret_cast<const uint4*>(
                    &wlds[row][4 * lane + 256 * j]);
                a = dot2(wu.x, su[j].x, a);
                a = dot2(wu.y, su[j].y, a);
                a = dot2(wu.z, su[j].z, a);
                a = dot2(wu.w, su[j].w, a);
            }
            acc[k] = a;
        }

        // ---- DPP full-wave reduce (4 rows), uniform results ----
        const float t0 = wave_sum(acc[0]);
        const float t1 = wave_sum(acc[1]);
        const float t2 = wave_sum(acc[2]);
        const float t3 = wave_sum(acc[3]);

        const float v0 = fast_tanh(t0) * INV_SQRT_N;
        const float v1 = fast_tanh(t1) * INV_SQRT_N;
        const float v2 = fast_tanh(t2) * INV_SQRT_N;
        const float v3 = fast_tanh(t3) * INV_SQRT_N;

        const int   wr0   = r0 + wave * ROWS_PER_WAVE;
        const int   slotn = (t + 1) & 1;
        const float phin  = (((t + 1) >> 1) & 1) ? -1.0f : 1.0f;
        if (lane == 0) {
            // 4 rows -> one 8B f16 packet
            uint2 pk;
            pk.x = pkrtz(phin * (v0 + ENC_OFF), phin * (v1 + ENC_OFF));
            pk.y = pkrtz(phin * (v2 + ENC_OFF), phin * (v3 + ENC_OFF));
            store_u2_coh(ring + (slotn << 10) + (wr0 >> 1), pk);
        } else if (lane == 2) {
            // per-wave f32 out store (rows wr0..wr0+3) — off the critical path
            *reinterpret_cast<float4*>(out + (size_t)(t + 1) * N_RES + wr0) =
                make_float4(v0, v1, v2, v3);
        }

        // ---- pin the small input-weight set across the back edge ----
        #pragma unroll
        for (int k = 0; k < ROWS_PER_WAVE; ++k) {
            #pragma unroll
            for (int i = 0; i < 4; ++i) KEEP2(wi2[k][i]);
        }

        #pragma unroll
        for (int i = 0; i < 4; ++i) xv[i] = xn[i];
    }
}

extern "C" void kernel_launch(void* const* d_in, const int* in_sizes, int n_in,
                              void* d_out, int out_size, void* d_ws, size_t ws_size,
                              hipStream_t stream) {
    const float* input  = (const float*)d_in[0];
    const float* state0 = (const float*)d_in[1];
    const float* W_in   = (const float*)d_in[2];
    const float* W_res  = (const float*)d_in[3];
    float* out = (float*)d_out;
    u32*  ring = (u32*)d_ws;

    // zero = "not ready" for both phases; re-cleared on every call/replay
    hipMemsetAsync(d_ws, 0, 2 * 1024 * sizeof(u32), stream);

    void* args[] = { (void*)&input, (void*)&state0, (void*)&W_in, (void*)&W_res,
                     (void*)&out, (void*)&ring };
    hipLaunchCooperativeKernel((const void*)reservoir_v17,
                               dim3(G_BLOCKS), dim3(B_THREADS),
                               args, 0, stream);
}